// Round 7
// baseline (232.774 us; speedup 1.0000x reference)
//
#include <hip/hip_runtime.h>
#include <hip/hip_bf16.h>

typedef __attribute__((ext_vector_type(8))) short bf16x8;    // 8 bf16 = 4 VGPR
typedef __attribute__((ext_vector_type(16))) float f32x16;   // 32x32 accumulator
typedef unsigned int u32;

#define MOD_SCALE 0.04419417382415922f     // 1/sqrt(512)
#define CONV_SCALE 0.014731391274719742f   // 1/sqrt(512*9)

__device__ __forceinline__ unsigned short f2bf(float f) {
  union { float f; u32 u; } v; v.f = f;
  u32 r = v.u + 0x7fffu + ((v.u >> 16) & 1u);   // RNE
  return (unsigned short)(r >> 16);
}

__device__ __forceinline__ void gload_lds16(const void* g, void* l) {
  __builtin_amdgcn_global_load_lds(
      (const __attribute__((address_space(1))) u32*)g,
      (__attribute__((address_space(3))) u32*)l, 16, 0, 0);
}

// ---- k_style: s[b][ic] = MOD_SCALE * (style[b] . mod_weight[ic]) + mod_bias[ic]
__global__ void k_style(const float* __restrict__ style, const float* __restrict__ mw,
                        const float* __restrict__ mb, float* __restrict__ s) {
  int idx = blockIdx.x * 256 + threadIdx.x;   // 4096 = b*512+ic
  int b = idx >> 9, ic = idx & 511;
  const float4* wr = (const float4*)(mw + ic * 512);
  const float4* sr = (const float4*)(style + b * 512);
  float acc = 0.f;
  #pragma unroll 4
  for (int k = 0; k < 128; ++k) {
    float4 a = wr[k], c = sr[k];
    acc += a.x * c.x + a.y * c.y + a.z * c.z + a.w * c.w;
  }
  s[idx] = acc * MOD_SCALE + mb[ic];
}

// ---- k_pre: [0,1024) weight prep -> wb; [1024,1536) xform -> xsb; [1536,1568) demod -> dscale.
// All paths read only k_style outputs / raw inputs: no intra-kernel ordering needed.
__global__ void k_pre(const float* __restrict__ wsrc, ushort* __restrict__ wb,
                      float* __restrict__ zerobuf, const float* __restrict__ x,
                      const float* __restrict__ s, ushort* __restrict__ xsb,
                      float* __restrict__ dscale) {
  __shared__ float wtile[2304];
  const int t = threadIdx.x;
  if (blockIdx.x < 1024) {
    // ---- weight prep: coalesced 2304-float tile -> wb[tap][icb][oc][ic16] bf16
    const float4* s4 = (const float4*)(wsrc + (size_t)blockIdx.x * 2304);
    float4* w4 = (float4*)wtile;
    w4[t] = s4[t];
    w4[t + 256] = s4[t + 256];
    if (t < 64) w4[t + 512] = s4[t + 512];
    __syncthreads();
    int idx = blockIdx.x * 256 + t;   // oc*512+ic
    int oc = idx >> 9, ic = idx & 511;
    int icb = ic >> 4, icr = ic & 15;
    if (blockIdx.x == 0 && t < 16) zerobuf[t] = 0.f;
    #pragma unroll
    for (int tap = 0; tap < 9; ++tap)
      wb[((tap * 32 + icb) * 512 + oc) * 16 + icr] = f2bf(wtile[t * 9 + tap]);
  } else if (blockIdx.x < 1536) {
    // ---- xform: xsb[b][y][icb 32][x 64][ic 16] = bf16(x[b][ic][y][x] * s[b][ic])
    int bid2 = blockIdx.x - 1024;
    const int y = bid2 & 63, b = bid2 >> 6;
    const int px = t & 63, icq = t >> 6;
    #pragma unroll
    for (int i = 0; i < 8; ++i) {
      int icb = i * 4 + icq;
      union { ushort u[16]; uint4 v[2]; } pk;
      #pragma unroll
      for (int j = 0; j < 16; ++j) {
        int ic = icb * 16 + j;
        float v = x[(b * 512 + ic) * 4096 + y * 64 + px] * s[b * 512 + ic];
        pk.u[j] = f2bf(v);
      }
      ushort* dst = xsb + ((size_t)((b * 64 + y) * 32 + icb) * 64 + px) * 16;
      *(uint4*)dst = pk.v[0];
      *(uint4*)(dst + 8) = pk.v[1];
    }
  } else {
    // ---- demod: dscale[b][oc] = CONV_SCALE * rsqrt(CONV_SCALE^2 * sum_ic wsq(oc,ic)*s^2 + eps)
    int bid3 = blockIdx.x - 1536;           // 32 blocks: (b, oc-octant of 128)
    int b = bid3 >> 2, og = bid3 & 3;
    float* ssq = wtile;                     // [512]
    float* part = wtile + 512;              // [256]
    {
      float v0 = s[b * 512 + t], v1 = s[b * 512 + t + 256];
      ssq[t] = v0 * v0;
      ssq[t + 256] = v1 * v1;
    }
    __syncthreads();
    const int oc = og * 128 + (t >> 1), ih = t & 1;
    const float4* wp = (const float4*)(wsrc + (size_t)oc * 4608 + ih * 2304);
    float acc = 0.f;
    #pragma unroll 2
    for (int si = 0; si < 64; ++si) {       // 4 ic (36 floats = 9 float4) per iter
      const int ic0 = ih * 256 + si * 4;
      float4 f0 = wp[si * 9 + 0], f1 = wp[si * 9 + 1], f2 = wp[si * 9 + 2];
      float4 f3 = wp[si * 9 + 3], f4v = wp[si * 9 + 4], f5 = wp[si * 9 + 5];
      float4 f6 = wp[si * 9 + 6], f7 = wp[si * 9 + 7], f8 = wp[si * 9 + 8];
      float g0 = ssq[ic0], g1 = ssq[ic0 + 1], g2 = ssq[ic0 + 2], g3 = ssq[ic0 + 3];
      float s0 = f0.x*f0.x + f0.y*f0.y + f0.z*f0.z + f0.w*f0.w
               + f1.x*f1.x + f1.y*f1.y + f1.z*f1.z + f1.w*f1.w + f2.x*f2.x;
      float s1 = f2.y*f2.y + f2.z*f2.z + f2.w*f2.w
               + f3.x*f3.x + f3.y*f3.y + f3.z*f3.z + f3.w*f3.w + f4v.x*f4v.x + f4v.y*f4v.y;
      float s2 = f4v.z*f4v.z + f4v.w*f4v.w + f5.x*f5.x + f5.y*f5.y + f5.z*f5.z + f5.w*f5.w
               + f6.x*f6.x + f6.y*f6.y + f6.z*f6.z;
      float s3 = f6.w*f6.w + f7.x*f7.x + f7.y*f7.y + f7.z*f7.z + f7.w*f7.w
               + f8.x*f8.x + f8.y*f8.y + f8.z*f8.z + f8.w*f8.w;
      acc += s0 * g0 + s1 * g1 + s2 * g2 + s3 * g3;
    }
    part[t] = acc;
    __syncthreads();
    if (t < 128) {
      float tot = part[2 * t] + part[2 * t + 1];
      dscale[b * 512 + og * 128 + t] = CONV_SCALE * rsqrtf(CONV_SCALE * CONV_SCALE * tot + 1e-8f);
    }
  }
}

// ---- k_conv: implicit-GEMM conv with mfma_f32_32x32x16_bf16 (R4 schedule).
// Block 64oc x 8rows x 64px, 4 waves; wave = 4 rows x 32 px x 64 oc (acc[4][2] f32x16).
// 36 LDS b128 reads per wave-step (18 A + 18 B) vs 42 in the 2rowx64px tile.
// BK=16, double-buffered; STAGE(t+1) issued before COMPUTE(t); 1 barrier/step.
#define ABYTES 18432
#define BBYTES 21120
#define BUFB   39552
#define SMEMSZ (2 * BUFB + 256)
__global__ __launch_bounds__(256, 2) void k_conv(
    const ushort* __restrict__ wb, const ushort* __restrict__ xsb,
    const float* __restrict__ dscale, const float* __restrict__ zerobuf,
    float* __restrict__ out) {
  const int yb = blockIdx.x, ocb = blockIdx.y, b = blockIdx.z;
  const int t = threadIdx.x;
  const int wv = t >> 6, l = t & 63;
  const int lc = l & 31, lh = l >> 5;
  const int wvr = wv >> 1, wvp = wv & 1;
  const int y0 = yb * 8, oc0 = ocb * 64;

  extern __shared__ char smem[];
  float* dss = (float*)(smem + 2 * BUFB);
  if (t < 64) dss[t] = dscale[b * 512 + oc0 + t];

  f32x16 acc[4][2];
  #pragma unroll
  for (int rr = 0; rr < 4; ++rr)
    #pragma unroll
    for (int ocf = 0; ocf < 2; ++ocf)
      #pragma unroll
      for (int k = 0; k < 16; ++k)
        acc[rr][ocf][k] = 0.f;

  // A staging: 1152 chunks (4 full iters + t<128)
  const char* asrc[5];
  #pragma unroll
  for (int i = 0; i < 5; ++i) {
    int cid = i * 256 + t;
    int tap = cid >> 7, cc = cid & 127;
    int oc_l = cc >> 1, h = cc & 1;
    asrc[i] = (const char*)wb + (size_t)tap * 524288 + (size_t)(oc0 + oc_l) * 32 + h * 16;
  }
  // B staging: 1320 chunks = 10 rows x 132 (cols 0,65 = zero border)
  const char* bsrc[6];
  int bstride[6];
  #pragma unroll
  for (int i = 0; i < 6; ++i) {
    int cid = i * 256 + t;
    int r = cid / 132, rem = cid - r * 132;
    int yy = y0 - 1 + r;
    bool interior = (rem >= 2) && (rem < 130) && ((unsigned)yy < 64u);
    bsrc[i] = interior
        ? (const char*)xsb + (size_t)(b * 64 + yy) * 65536 + (rem - 2) * 16
        : (const char*)zerobuf;
    bstride[i] = interior ? 2048 : 0;
  }

  const int apo = (lc * 2 + lh) * 16;
  const int bco = (wvp * 32 + lc) * 32 + lh * 16;

  auto STAGE = [&](int bo, int icb) {
    char* Ab = smem + bo;
    char* Bb = Ab + ABYTES;
    const int aoff = icb * 16384;
    #pragma unroll
    for (int i = 0; i < 4; ++i)
      gload_lds16(asrc[i] + aoff, Ab + i * 4096 + wv * 1024);
    if (t < 128)
      gload_lds16(asrc[4] + aoff, Ab + 16384 + wv * 1024);
    #pragma unroll
    for (int i = 0; i < 5; ++i)
      gload_lds16(bsrc[i] + icb * bstride[i], Bb + i * 4096 + wv * 1024);
    if (t < 40)
      gload_lds16(bsrc[5] + icb * bstride[5], Bb + 20480);
  };

  auto COMPUTE = [&](int bo) {
    const char* Ab = smem + bo;
    const char* Bb = smem + bo + ABYTES;
    #pragma unroll
    for (int dx = 0; dx < 3; ++dx) {
      bf16x8 bfr[6];
      #pragma unroll
      for (int j = 0; j < 6; ++j)
        bfr[j] = *(const bf16x8*)(Bb + (wvr * 4 + j) * 2112 + dx * 32 + bco);
      bf16x8 af[3][2];
      #pragma unroll
      for (int dy = 0; dy < 3; ++dy)
        #pragma unroll
        for (int ocf = 0; ocf < 2; ++ocf)
          af[dy][ocf] = *(const bf16x8*)(Ab + (dy * 3 + dx) * 2048 + ocf * 1024 + apo);
      #pragma unroll
      for (int dy = 0; dy < 3; ++dy)
        #pragma unroll
        for (int rr = 0; rr < 4; ++rr)
          #pragma unroll
          for (int ocf = 0; ocf < 2; ++ocf)
            acc[rr][ocf] = __builtin_amdgcn_mfma_f32_32x32x16_bf16(
                af[dy][ocf], bfr[rr + dy], acc[rr][ocf], 0, 0, 0);
    }
  };

  STAGE(0, 0);
  __syncthreads();
  #pragma unroll 1
  for (int it = 0; it < 32; it += 2) {
    STAGE(BUFB, it + 1);
    COMPUTE(0);
    __syncthreads();
    if (it < 30) STAGE(0, it + 2);
    COMPUTE(BUFB);
    __syncthreads();
  }

  // ---- epilogue: 32x32 D layout [m74/m101]: col(px)=lane&31, row(oc)=(reg&3)+8*(reg>>2)+4*(lane>>5)
  #pragma unroll
  for (int rr = 0; rr < 4; ++rr) {
    const int y_row = y0 + wvr * 4 + rr;
    #pragma unroll
    for (int ocf = 0; ocf < 2; ++ocf) {
      #pragma unroll
      for (int reg = 0; reg < 16; ++reg) {
        int oc_l = ocf * 32 + (reg & 3) + 8 * (reg >> 2) + 4 * lh;
        out[(size_t)(b * 512 + oc0 + oc_l) * 4096 + y_row * 64 + wvp * 32 + lc]
            = acc[rr][ocf][reg] * dss[oc_l];
      }
    }
  }
}

extern "C" void kernel_launch(void* const* d_in, const int* in_sizes, int n_in,
                              void* d_out, int out_size, void* d_ws, size_t ws_size,
                              hipStream_t stream) {
  const float* x     = (const float*)d_in[0];  // [8,512,64,64]
  const float* style = (const float*)d_in[1];  // [8,512]
  const float* mw    = (const float*)d_in[2];  // [512,512]
  const float* mb    = (const float*)d_in[3];  // [512]
  const float* wsrc  = (const float*)d_in[4];  // [1,512,512,3,3]
  float* out = (float*)d_out;

  char* ws = (char*)d_ws;
  float*  zerobuf = (float*)(ws + 0);          //    64 B
  float*  s       = (float*)(ws + 256);        //  16 KB
  float*  dscale  = (float*)(ws + 16640);      //  16 KB
  ushort* wb      = (ushort*)(ws + 1081600);   // 4.5 MB  [9][32][512][16] bf16
  ushort* xsb     = (ushort*)(ws + 5800192);   //  32 MB  [8][64][32][64][16] bf16

  hipFuncSetAttribute(reinterpret_cast<const void*>(k_conv),
                      hipFuncAttributeMaxDynamicSharedMemorySize, SMEMSZ);

  k_style<<<dim3(16), dim3(256), 0, stream>>>(style, mw, mb, s);
  k_pre<<<dim3(1568), dim3(256), 0, stream>>>(wsrc, wb, zerobuf, x, s, xsb, dscale);
  k_conv<<<dim3(8, 8, 8), dim3(256), SMEMSZ, stream>>>(wb, xsb, dscale, zerobuf, out);
}

// Round 8
// 196.739 us; speedup vs baseline: 1.1832x; 1.1832x over previous
//
#include <hip/hip_runtime.h>
#include <hip/hip_bf16.h>

typedef __attribute__((ext_vector_type(8))) short bf16x8;    // 8 bf16 = 4 VGPR
typedef __attribute__((ext_vector_type(16))) float f32x16;   // 32x32 accumulator
typedef unsigned int u32;

#define MOD_SCALE 0.04419417382415922f     // 1/sqrt(512)
#define CONV_SCALE 0.014731391274719742f   // 1/sqrt(512*9)

__device__ __forceinline__ unsigned short f2bf(float f) {
  union { float f; u32 u; } v; v.f = f;
  u32 r = v.u + 0x7fffu + ((v.u >> 16) & 1u);   // RNE
  return (unsigned short)(r >> 16);
}

__device__ __forceinline__ void gload_lds16(const void* g, void* l) {
  __builtin_amdgcn_global_load_lds(
      (const __attribute__((address_space(1))) u32*)g,
      (__attribute__((address_space(3))) u32*)l, 16, 0, 0);
}

// ---- k_style: s[b][ic] = MOD_SCALE * (style[b] . mod_weight[ic]) + mod_bias[ic]
__global__ void k_style(const float* __restrict__ style, const float* __restrict__ mw,
                        const float* __restrict__ mb, float* __restrict__ s) {
  int idx = blockIdx.x * 256 + threadIdx.x;   // 4096 = b*512+ic
  int b = idx >> 9, ic = idx & 511;
  const float4* wr = (const float4*)(mw + ic * 512);
  const float4* sr = (const float4*)(style + b * 512);
  float acc = 0.f;
  #pragma unroll 4
  for (int k = 0; k < 128; ++k) {
    float4 a = wr[k], c = sr[k];
    acc += a.x * c.x + a.y * c.y + a.z * c.z + a.w * c.w;
  }
  s[idx] = acc * MOD_SCALE + mb[ic];
}

// ---- k_prep: 1024 blocks weight prep (wb + wsq + zerobuf), coalesced via LDS tile.
// wb layout: [tap 9][icb 32][oc 512][ic 16] bf16.
__global__ void k_prep(const float* __restrict__ wsrc, ushort* __restrict__ wb,
                       float* __restrict__ wsq, float* __restrict__ zerobuf) {
  __shared__ float wtile[2304];
  const int t = threadIdx.x;
  const float4* s4 = (const float4*)(wsrc + (size_t)blockIdx.x * 2304);
  float4* w4 = (float4*)wtile;
  w4[t] = s4[t];
  w4[t + 256] = s4[t + 256];
  if (t < 64) w4[t + 512] = s4[t + 512];
  __syncthreads();
  int idx = blockIdx.x * 256 + t;   // oc*512+ic
  int oc = idx >> 9, ic = idx & 511;
  int icb = ic >> 4, icr = ic & 15;
  if (blockIdx.x == 0 && t < 16) zerobuf[t] = 0.f;
  float sq = 0.f;
  #pragma unroll
  for (int tap = 0; tap < 9; ++tap) {
    float v = wtile[t * 9 + tap];
    sq += v * v;
    wb[((tap * 32 + icb) * 512 + oc) * 16 + icr] = f2bf(v);
  }
  wsq[idx] = sq;
}

// ---- k_pre2: [0,512) xform -> xsb; [512,528) demod -> dscale (uses wsq + s).
__global__ void k_pre2(const float* __restrict__ x, const float* __restrict__ s,
                       ushort* __restrict__ xsb, const float* __restrict__ wsq,
                       float* __restrict__ dscale) {
  const int t = threadIdx.x;
  if (blockIdx.x < 512) {
    // xform: xsb[b][y][icb 32][x 64][ic 16] = bf16(x[b][ic][y][x] * s[b][ic])
    const int y = blockIdx.x & 63, b = blockIdx.x >> 6;
    const int px = t & 63, icq = t >> 6;
    #pragma unroll
    for (int i = 0; i < 8; ++i) {
      int icb = i * 4 + icq;
      union { ushort u[16]; uint4 v[2]; } pk;
      #pragma unroll
      for (int j = 0; j < 16; ++j) {
        int ic = icb * 16 + j;
        float v = x[(b * 512 + ic) * 4096 + y * 64 + px] * s[b * 512 + ic];
        pk.u[j] = f2bf(v);
      }
      ushort* dst = xsb + ((size_t)((b * 64 + y) * 32 + icb) * 64 + px) * 16;
      *(uint4*)dst = pk.v[0];
      *(uint4*)(dst + 8) = pk.v[1];
    }
  } else {
    // demod: dscale[b][oc] = CONV_SCALE * rsqrt(CONV_SCALE^2 * sum_ic wsq*s^2 + eps)
    int idx = (blockIdx.x - 512) * 256 + t;   // 4096 = b*512+oc
    int b = idx >> 9, oc = idx & 511;
    const float4* wq = (const float4*)(wsq + oc * 512);
    const float4* sp = (const float4*)(s + b * 512);
    float acc = 0.f;
    #pragma unroll 4
    for (int k = 0; k < 128; ++k) {
      float4 a = wq[k], c = sp[k];
      acc += a.x * c.x * c.x + a.y * c.y * c.y + a.z * c.z * c.z + a.w * c.w * c.w;
    }
    dscale[idx] = CONV_SCALE * rsqrtf(CONV_SCALE * CONV_SCALE * acc + 1e-8f);
  }
}

// ---- k_conv: implicit-GEMM conv, mfma_f32_32x32x16_bf16.
// Block 64oc x 8rows x 64px, 4 waves; wave = 4rows x 32px x 64oc, acc[4][2] f32x16.
// A (weights) NEVER staged in LDS: each wave loads its A-frags as contiguous 1KB
// coalesced global loads from wb (L2-resident; ocb pinned to XCD via id&7 decode),
// double-buffered one dx-phase ahead. LDS holds only B (2 x 21120B). STAGE(t+1)
// before COMPUTE(t), one barrier per K-step. setprio around MFMA clusters.
#define BUFB   21120
#define SMEMSZ (2 * BUFB + 256)
__global__ __launch_bounds__(256, 2) void k_conv(
    const ushort* __restrict__ wb, const ushort* __restrict__ xsb,
    const float* __restrict__ dscale, const float* __restrict__ zerobuf,
    float* __restrict__ out) {
  const int id = blockIdx.x;
  const int ocb = id & 7, yb = (id >> 3) & 7, b = id >> 6;   // ocb<->XCD pinning
  const int t = threadIdx.x;
  const int wv = t >> 6, l = t & 63;
  const int lc = l & 31, lh = l >> 5;
  const int wvr = wv >> 1, wvp = wv & 1;
  const int y0 = yb * 8, oc0 = ocb * 64;

  extern __shared__ char smem[];
  float* dss = (float*)(smem + 2 * BUFB);
  if (t < 64) dss[t] = dscale[b * 512 + oc0 + t];

  f32x16 acc[4][2];
  #pragma unroll
  for (int rr = 0; rr < 4; ++rr)
    #pragma unroll
    for (int ocf = 0; ocf < 2; ++ocf)
      #pragma unroll
      for (int k = 0; k < 16; ++k)
        acc[rr][ocf][k] = 0.f;

  // per-tap A base pointers (lane offset folded in): frag(tap,icb,ocf) is the
  // contiguous 1KB at atap[tap] + icb*16384 + ocf*1024
  const int alane = lc * 32 + lh * 16;
  const char* atap[9];
  #pragma unroll
  for (int tap = 0; tap < 9; ++tap)
    atap[tap] = (const char*)wb + (size_t)tap * 524288 + (size_t)oc0 * 32 + alane;

  // B staging: 1320 chunks = 10 rows x 132 (cols 0,1,130,131 = zero border)
  const char* bsrc[6];
  int bstride[6];
  #pragma unroll
  for (int i = 0; i < 6; ++i) {
    int cid = i * 256 + t;
    int r = cid / 132, rem = cid - r * 132;
    int yy = y0 - 1 + r;
    bool interior = (rem >= 2) && (rem < 130) && ((unsigned)yy < 64u);
    bsrc[i] = interior
        ? (const char*)xsb + (size_t)(b * 64 + yy) * 65536 + (rem - 2) * 16
        : (const char*)zerobuf;
    bstride[i] = interior ? 2048 : 0;
  }

  const int bco = (wvp * 32 + lc) * 32 + lh * 16;

  auto STAGE = [&](int bo, int icb) {
    char* Bb = smem + bo;
    #pragma unroll
    for (int i = 0; i < 5; ++i)
      gload_lds16(bsrc[i] + icb * bstride[i], Bb + i * 4096 + wv * 1024);
    if (t < 40)
      gload_lds16(bsrc[5] + icb * bstride[5], Bb + 20480);
  };

  #define LOADA(buf, dx_, icb_)                                                 \
    {                                                                           \
      _Pragma("unroll")                                                         \
      for (int dy = 0; dy < 3; ++dy)                                            \
        _Pragma("unroll")                                                       \
        for (int ocf = 0; ocf < 2; ++ocf)                                       \
          buf[dy][ocf] = *(const bf16x8*)(atap[(dx_) + dy * 3] +                \
                                          (size_t)(icb_) * 16384 + ocf * 1024); \
    }

  #define PHASE(Bb_, dx_, afc, afn, nicb, ndx)                                  \
    {                                                                           \
      LOADA(afn, ndx, nicb);                                                    \
      bf16x8 bfr[6];                                                            \
      _Pragma("unroll")                                                         \
      for (int j = 0; j < 6; ++j)                                               \
        bfr[j] = *(const bf16x8*)((Bb_) + (wvr * 4 + j) * 2112 + (dx_)*32 + bco); \
      __builtin_amdgcn_s_setprio(1);                                            \
      _Pragma("unroll")                                                         \
      for (int dy = 0; dy < 3; ++dy)                                            \
        _Pragma("unroll")                                                       \
        for (int rr = 0; rr < 4; ++rr)                                          \
          _Pragma("unroll")                                                     \
          for (int ocf = 0; ocf < 2; ++ocf)                                     \
            acc[rr][ocf] = __builtin_amdgcn_mfma_f32_32x32x16_bf16(             \
                afc[dy][ocf], bfr[rr + dy], acc[rr][ocf], 0, 0, 0);             \
      __builtin_amdgcn_s_setprio(0);                                            \
    }

  bf16x8 afA[3][2], afB[3][2];
  STAGE(0, 0);
  LOADA(afA, 0, 0);
  __syncthreads();

  #pragma unroll 1
  for (int it = 0; it < 32; it += 2) {
    const char* Bb0 = smem;
    const char* Bb1 = smem + BUFB;
    STAGE(BUFB, it + 1);
    PHASE(Bb0, 0, afA, afB, it, 1);
    PHASE(Bb0, 1, afB, afA, it, 2);
    PHASE(Bb0, 2, afA, afB, it + 1, 0);
    __syncthreads();
    if (it < 30) STAGE(0, it + 2);
    PHASE(Bb1, 0, afB, afA, it + 1, 1);
    PHASE(Bb1, 1, afA, afB, it + 1, 2);
    PHASE(Bb1, 2, afB, afA, it + 2, 0);   // last iter: benign OOB-read within ws
    __syncthreads();
  }

  // ---- epilogue: 32x32 D layout [m74/m101]: col(px)=lane&31, row(oc)=(reg&3)+8*(reg>>2)+4*(lane>>5)
  #pragma unroll
  for (int rr = 0; rr < 4; ++rr) {
    const int y_row = y0 + wvr * 4 + rr;
    #pragma unroll
    for (int ocf = 0; ocf < 2; ++ocf) {
      #pragma unroll
      for (int reg = 0; reg < 16; ++reg) {
        int oc_l = ocf * 32 + (reg & 3) + 8 * (reg >> 2) + 4 * lh;
        out[(size_t)(b * 512 + oc0 + oc_l) * 4096 + y_row * 64 + wvp * 32 + lc]
            = acc[rr][ocf][reg] * dss[oc_l];
      }
    }
  }
}

extern "C" void kernel_launch(void* const* d_in, const int* in_sizes, int n_in,
                              void* d_out, int out_size, void* d_ws, size_t ws_size,
                              hipStream_t stream) {
  const float* x     = (const float*)d_in[0];  // [8,512,64,64]
  const float* style = (const float*)d_in[1];  // [8,512]
  const float* mw    = (const float*)d_in[2];  // [512,512]
  const float* mb    = (const float*)d_in[3];  // [512]
  const float* wsrc  = (const float*)d_in[4];  // [1,512,512,3,3]
  float* out = (float*)d_out;

  char* ws = (char*)d_ws;
  float*  zerobuf = (float*)(ws + 0);          //    64 B
  float*  s       = (float*)(ws + 256);        //  16 KB
  float*  dscale  = (float*)(ws + 16640);      //  16 KB
  float*  wsq     = (float*)(ws + 33024);      //   1 MB
  ushort* wb      = (ushort*)(ws + 1081600);   // 4.5 MB  [9][32][512][16] bf16
  ushort* xsb     = (ushort*)(ws + 5800192);   //  32 MB  [8][64][32][64][16] bf16

  hipFuncSetAttribute(reinterpret_cast<const void*>(k_conv),
                      hipFuncAttributeMaxDynamicSharedMemorySize, SMEMSZ);

  k_style<<<dim3(16), dim3(256), 0, stream>>>(style, mw, mb, s);
  k_prep<<<dim3(1024), dim3(256), 0, stream>>>(wsrc, wb, wsq, zerobuf);
  k_pre2<<<dim3(528), dim3(256), 0, stream>>>(x, s, xsb, wsq, dscale);
  k_conv<<<dim3(512), dim3(256), SMEMSZ, stream>>>(wb, xsb, dscale, zerobuf, out);
}

// Round 9
// 188.880 us; speedup vs baseline: 1.2324x; 1.0416x over previous
//
#include <hip/hip_runtime.h>
#include <hip/hip_bf16.h>

typedef __attribute__((ext_vector_type(8))) short bf16x8;    // 8 bf16 = 4 VGPR
typedef __attribute__((ext_vector_type(16))) float f32x16;   // 32x32 accumulator
typedef unsigned int u32;

#define MOD_SCALE 0.04419417382415922f     // 1/sqrt(512)
#define CONV_SCALE 0.014731391274719742f   // 1/sqrt(512*9)

__device__ __forceinline__ unsigned short f2bf(float f) {
  union { float f; u32 u; } v; v.f = f;
  u32 r = v.u + 0x7fffu + ((v.u >> 16) & 1u);   // RNE
  return (unsigned short)(r >> 16);
}

__device__ __forceinline__ void gload_lds16(const void* g, void* l) {
  __builtin_amdgcn_global_load_lds(
      (const __attribute__((address_space(1))) u32*)g,
      (__attribute__((address_space(3))) u32*)l, 16, 0, 0);
}

// ---- k_prep: blocks 0..1023 = weight prep (LDS-coalesced), 1024..1039 = style GEMV.
// wb layout: [tap 9][icb 32][oc 512][ic 16] bf16.
__global__ void k_prep(const float* __restrict__ wsrc, ushort* __restrict__ wb,
                       float* __restrict__ wsq, float* __restrict__ zerobuf,
                       const float* __restrict__ style, const float* __restrict__ mw,
                       const float* __restrict__ mb, float* __restrict__ s) {
  __shared__ float wtile[2304];
  const int t = threadIdx.x;
  if (blockIdx.x < 1024) {
    const float4* s4 = (const float4*)(wsrc + (size_t)blockIdx.x * 2304);
    float4* w4 = (float4*)wtile;
    w4[t] = s4[t];
    w4[t + 256] = s4[t + 256];
    if (t < 64) w4[t + 512] = s4[t + 512];
    __syncthreads();
    int idx = blockIdx.x * 256 + t;   // oc*512+ic
    int oc = idx >> 9, ic = idx & 511;
    int icb = ic >> 4, icr = ic & 15;
    if (blockIdx.x == 0 && t < 16) zerobuf[t] = 0.f;
    float sq = 0.f;
    #pragma unroll
    for (int tap = 0; tap < 9; ++tap) {
      float v = wtile[t * 9 + tap];
      sq += v * v;
      wb[((tap * 32 + icb) * 512 + oc) * 16 + icr] = f2bf(v);
    }
    wsq[idx] = sq;
  } else {
    int idx = (blockIdx.x - 1024) * 256 + t;   // b*512+ic
    int b = idx >> 9, ic = idx & 511;
    const float4* wr = (const float4*)(mw + ic * 512);
    const float4* sr = (const float4*)(style + b * 512);
    float acc = 0.f;
    #pragma unroll 4
    for (int k = 0; k < 128; ++k) {
      float4 a = wr[k], c = sr[k];
      acc += a.x * c.x + a.y * c.y + a.z * c.z + a.w * c.w;
    }
    s[idx] = acc * MOD_SCALE + mb[ic];
  }
}

// ---- k_pre2: [0,512) xform -> xsb; [512,528) demod -> dscale (uses wsq + s).
__global__ void k_pre2(const float* __restrict__ x, const float* __restrict__ s,
                       ushort* __restrict__ xsb, const float* __restrict__ wsq,
                       float* __restrict__ dscale) {
  const int t = threadIdx.x;
  if (blockIdx.x < 512) {
    // xform: xsb[b][y][icb 32][x 64][ic 16] = bf16(x[b][ic][y][x] * s[b][ic])
    const int y = blockIdx.x & 63, b = blockIdx.x >> 6;
    const int px = t & 63, icq = t >> 6;
    #pragma unroll
    for (int i = 0; i < 8; ++i) {
      int icb = i * 4 + icq;
      union { ushort u[16]; uint4 v[2]; } pk;
      #pragma unroll
      for (int j = 0; j < 16; ++j) {
        int ic = icb * 16 + j;
        float v = x[(b * 512 + ic) * 4096 + y * 64 + px] * s[b * 512 + ic];
        pk.u[j] = f2bf(v);
      }
      ushort* dst = xsb + ((size_t)((b * 64 + y) * 32 + icb) * 64 + px) * 16;
      *(uint4*)dst = pk.v[0];
      *(uint4*)(dst + 8) = pk.v[1];
    }
  } else {
    // demod: dscale[b][oc] = CONV_SCALE * rsqrt(CONV_SCALE^2 * sum_ic wsq*s^2 + eps)
    int idx = (blockIdx.x - 512) * 256 + t;   // 4096 = b*512+oc
    int b = idx >> 9, oc = idx & 511;
    const float4* wq = (const float4*)(wsq + oc * 512);
    const float4* sp = (const float4*)(s + b * 512);
    float acc = 0.f;
    #pragma unroll 4
    for (int k = 0; k < 128; ++k) {
      float4 a = wq[k], c = sp[k];
      acc += a.x * c.x * c.x + a.y * c.y * c.y + a.z * c.z * c.z + a.w * c.w * c.w;
    }
    dscale[idx] = CONV_SCALE * rsqrtf(CONV_SCALE * CONV_SCALE * acc + 1e-8f);
  }
}

// ---- k_conv: implicit-GEMM conv, mfma_f32_32x32x16_bf16 (R7 structure).
// Block 64oc x 8rows x 64px, 4 waves; wave = 4rows x 32px x 64oc, acc[4][2] f32x16.
// BK=16, A+B LDS double-buffered; STAGE(t+1) before COMPUTE(t); 1 barrier/step.
// NEW: per-block K-phase rotation (break cross-block phase-lock), B-frag register
// prefetch across dx, setprio around MFMA clusters.
#define ABYTES 18432
#define BUFB   39552
#define SMEMSZ (2 * BUFB + 256)
__global__ __launch_bounds__(256, 2) void k_conv(
    const ushort* __restrict__ wb, const ushort* __restrict__ xsb,
    const float* __restrict__ dscale, const float* __restrict__ zerobuf,
    float* __restrict__ out) {
  const int yb = blockIdx.x, ocb = blockIdx.y, b = blockIdx.z;
  const int t = threadIdx.x;
  const int wv = t >> 6, l = t & 63;
  const int lc = l & 31, lh = l >> 5;
  const int wvr = wv >> 1, wvp = wv & 1;
  const int y0 = yb * 8, oc0 = ocb * 64;
  const int ph = ((b ^ yb ^ ocb) & 1) << 4;   // K-phase rotation: 0 or 16

  extern __shared__ char smem[];
  float* dss = (float*)(smem + 2 * BUFB);
  if (t < 64) dss[t] = dscale[b * 512 + oc0 + t];

  f32x16 acc[4][2];
  #pragma unroll
  for (int rr = 0; rr < 4; ++rr)
    #pragma unroll
    for (int ocf = 0; ocf < 2; ++ocf)
      #pragma unroll
      for (int k = 0; k < 16; ++k)
        acc[rr][ocf][k] = 0.f;

  // A staging: 1152 chunks (4 full iters + t<128)
  const char* asrc[5];
  #pragma unroll
  for (int i = 0; i < 5; ++i) {
    int cid = i * 256 + t;
    int tap = cid >> 7, cc = cid & 127;
    int oc_l = cc >> 1, h = cc & 1;
    asrc[i] = (const char*)wb + (size_t)tap * 524288 + (size_t)(oc0 + oc_l) * 32 + h * 16;
  }
  // B staging: 1320 chunks = 10 rows x 132 (cols 0,1,130,131 = zero border)
  const char* bsrc[6];
  int bstride[6];
  #pragma unroll
  for (int i = 0; i < 6; ++i) {
    int cid = i * 256 + t;
    int r = cid / 132, rem = cid - r * 132;
    int yy = y0 - 1 + r;
    bool interior = (rem >= 2) && (rem < 130) && ((unsigned)yy < 64u);
    bsrc[i] = interior
        ? (const char*)xsb + (size_t)(b * 64 + yy) * 65536 + (rem - 2) * 16
        : (const char*)zerobuf;
    bstride[i] = interior ? 2048 : 0;
  }

  const int apo = (lc * 2 + lh) * 16;
  const int bco = (wvp * 32 + lc) * 32 + lh * 16;

  auto STAGE = [&](int bo, int icb) {
    char* Ab = smem + bo;
    char* Bb = Ab + ABYTES;
    const int aoff = icb * 16384;
    #pragma unroll
    for (int i = 0; i < 4; ++i)
      gload_lds16(asrc[i] + aoff, Ab + i * 4096 + wv * 1024);
    if (t < 128)
      gload_lds16(asrc[4] + aoff, Ab + 16384 + wv * 1024);
    #pragma unroll
    for (int i = 0; i < 5; ++i)
      gload_lds16(bsrc[i] + icb * bstride[i], Bb + i * 4096 + wv * 1024);
    if (t < 40)
      gload_lds16(bsrc[5] + icb * bstride[5], Bb + 20480);
  };

  auto COMPUTE = [&](int bo) {
    const char* Ab = smem + bo;
    const char* Bb = smem + bo + ABYTES;
    bf16x8 fb[2][6];
    #pragma unroll
    for (int j = 0; j < 6; ++j)
      fb[0][j] = *(const bf16x8*)(Bb + (wvr * 4 + j) * 2112 + bco);
    #pragma unroll
    for (int dx = 0; dx < 3; ++dx) {
      if (dx < 2) {
        #pragma unroll
        for (int j = 0; j < 6; ++j)
          fb[(dx + 1) & 1][j] =
              *(const bf16x8*)(Bb + (wvr * 4 + j) * 2112 + (dx + 1) * 32 + bco);
      }
      bf16x8 af[3][2];
      #pragma unroll
      for (int dy = 0; dy < 3; ++dy)
        #pragma unroll
        for (int ocf = 0; ocf < 2; ++ocf)
          af[dy][ocf] = *(const bf16x8*)(Ab + (dy * 3 + dx) * 2048 + ocf * 1024 + apo);
      __builtin_amdgcn_s_setprio(1);
      #pragma unroll
      for (int dy = 0; dy < 3; ++dy)
        #pragma unroll
        for (int rr = 0; rr < 4; ++rr)
          #pragma unroll
          for (int ocf = 0; ocf < 2; ++ocf)
            acc[rr][ocf] = __builtin_amdgcn_mfma_f32_32x32x16_bf16(
                af[dy][ocf], fb[dx & 1][rr + dy], acc[rr][ocf], 0, 0, 0);
      __builtin_amdgcn_s_setprio(0);
    }
  };

  STAGE(0, ph);
  __syncthreads();
  #pragma unroll 1
  for (int it = 0; it < 32; it += 2) {
    STAGE(BUFB, (it + 1 + ph) & 31);
    COMPUTE(0);
    __syncthreads();
    if (it < 30) STAGE(0, (it + 2 + ph) & 31);
    COMPUTE(BUFB);
    __syncthreads();
  }

  // ---- epilogue: 32x32 D layout [m74/m101]: col(px)=lane&31, row(oc)=(reg&3)+8*(reg>>2)+4*(lane>>5)
  #pragma unroll
  for (int rr = 0; rr < 4; ++rr) {
    const int y_row = y0 + wvr * 4 + rr;
    #pragma unroll
    for (int ocf = 0; ocf < 2; ++ocf) {
      #pragma unroll
      for (int reg = 0; reg < 16; ++reg) {
        int oc_l = ocf * 32 + (reg & 3) + 8 * (reg >> 2) + 4 * lh;
        out[(size_t)(b * 512 + oc0 + oc_l) * 4096 + y_row * 64 + wvp * 32 + lc]
            = acc[rr][ocf][reg] * dss[oc_l];
      }
    }
  }
}

extern "C" void kernel_launch(void* const* d_in, const int* in_sizes, int n_in,
                              void* d_out, int out_size, void* d_ws, size_t ws_size,
                              hipStream_t stream) {
  const float* x     = (const float*)d_in[0];  // [8,512,64,64]
  const float* style = (const float*)d_in[1];  // [8,512]
  const float* mw    = (const float*)d_in[2];  // [512,512]
  const float* mb    = (const float*)d_in[3];  // [512]
  const float* wsrc  = (const float*)d_in[4];  // [1,512,512,3,3]
  float* out = (float*)d_out;

  char* ws = (char*)d_ws;
  float*  zerobuf = (float*)(ws + 0);          //    64 B
  float*  s       = (float*)(ws + 256);        //  16 KB
  float*  dscale  = (float*)(ws + 16640);      //  16 KB
  float*  wsq     = (float*)(ws + 33024);      //   1 MB
  ushort* wb      = (ushort*)(ws + 1081600);   // 4.5 MB  [9][32][512][16] bf16
  ushort* xsb     = (ushort*)(ws + 5800192);   //  32 MB  [8][64][32][64][16] bf16

  hipFuncSetAttribute(reinterpret_cast<const void*>(k_conv),
                      hipFuncAttributeMaxDynamicSharedMemorySize, SMEMSZ);

  k_prep<<<dim3(1040), dim3(256), 0, stream>>>(wsrc, wb, wsq, zerobuf, style, mw, mb, s);
  k_pre2<<<dim3(528), dim3(256), 0, stream>>>(x, s, xsb, wsq, dscale);
  k_conv<<<dim3(8, 8, 8), dim3(256), SMEMSZ, stream>>>(wb, xsb, dscale, zerobuf, out);
}

// Round 10
// 181.052 us; speedup vs baseline: 1.2857x; 1.0432x over previous
//
#include <hip/hip_runtime.h>
#include <hip/hip_bf16.h>

typedef __attribute__((ext_vector_type(8))) short bf16x8;    // 8 bf16 = 4 VGPR
typedef __attribute__((ext_vector_type(16))) float f32x16;   // 32x32 accumulator
typedef unsigned int u32;

#define MOD_SCALE 0.04419417382415922f     // 1/sqrt(512)
#define CONV_SCALE 0.014731391274719742f   // 1/sqrt(512*9)

__device__ __forceinline__ unsigned short f2bf(float f) {
  union { float f; u32 u; } v; v.f = f;
  u32 r = v.u + 0x7fffu + ((v.u >> 16) & 1u);   // RNE
  return (unsigned short)(r >> 16);
}

__device__ __forceinline__ void gload_lds16(const void* g, void* l) {
  __builtin_amdgcn_global_load_lds(
      (const __attribute__((address_space(1))) u32*)g,
      (__attribute__((address_space(3))) u32*)l, 16, 0, 0);
}

// ---- k_prep: blocks 0..1023 = weight prep (LDS-coalesced), 1024..1039 = style GEMV.
// wb layout: [tap 9][icb 32][oc 512][ic 16] bf16.
__global__ void k_prep(const float* __restrict__ wsrc, ushort* __restrict__ wb,
                       float* __restrict__ wsq, float* __restrict__ zerobuf,
                       const float* __restrict__ style, const float* __restrict__ mw,
                       const float* __restrict__ mb, float* __restrict__ s) {
  __shared__ float wtile[2304];
  const int t = threadIdx.x;
  if (blockIdx.x < 1024) {
    const float4* s4 = (const float4*)(wsrc + (size_t)blockIdx.x * 2304);
    float4* w4 = (float4*)wtile;
    w4[t] = s4[t];
    w4[t + 256] = s4[t + 256];
    if (t < 64) w4[t + 512] = s4[t + 512];
    __syncthreads();
    int idx = blockIdx.x * 256 + t;   // oc*512+ic
    int oc = idx >> 9, ic = idx & 511;
    int icb = ic >> 4, icr = ic & 15;
    if (blockIdx.x == 0 && t < 16) zerobuf[t] = 0.f;
    float sq = 0.f;
    #pragma unroll
    for (int tap = 0; tap < 9; ++tap) {
      float v = wtile[t * 9 + tap];
      sq += v * v;
      wb[((tap * 32 + icb) * 512 + oc) * 16 + icr] = f2bf(v);
    }
    wsq[idx] = sq;
  } else {
    int idx = (blockIdx.x - 1024) * 256 + t;   // b*512+ic
    int b = idx >> 9, ic = idx & 511;
    const float4* wr = (const float4*)(mw + ic * 512);
    const float4* sr = (const float4*)(style + b * 512);
    float acc = 0.f;
    #pragma unroll 4
    for (int k = 0; k < 128; ++k) {
      float4 a = wr[k], c = sr[k];
      acc += a.x * c.x + a.y * c.y + a.z * c.z + a.w * c.w;
    }
    s[idx] = acc * MOD_SCALE + mb[ic];
  }
}

// ---- k_pre2: [0,512) xform -> xsb; [512,528) demod -> dscale (uses wsq + s).
__global__ void k_pre2(const float* __restrict__ x, const float* __restrict__ s,
                       ushort* __restrict__ xsb, const float* __restrict__ wsq,
                       float* __restrict__ dscale) {
  const int t = threadIdx.x;
  if (blockIdx.x < 512) {
    // xform: xsb[b][y][icb 32][x 64][ic 16] = bf16(x[b][ic][y][x] * s[b][ic])
    const int y = blockIdx.x & 63, b = blockIdx.x >> 6;
    const int px = t & 63, icq = t >> 6;
    #pragma unroll
    for (int i = 0; i < 8; ++i) {
      int icb = i * 4 + icq;
      union { ushort u[16]; uint4 v[2]; } pk;
      #pragma unroll
      for (int j = 0; j < 16; ++j) {
        int ic = icb * 16 + j;
        float v = x[(b * 512 + ic) * 4096 + y * 64 + px] * s[b * 512 + ic];
        pk.u[j] = f2bf(v);
      }
      ushort* dst = xsb + ((size_t)((b * 64 + y) * 32 + icb) * 64 + px) * 16;
      *(uint4*)dst = pk.v[0];
      *(uint4*)(dst + 8) = pk.v[1];
    }
  } else {
    // demod: dscale[b][oc] = CONV_SCALE * rsqrt(CONV_SCALE^2 * sum_ic wsq*s^2 + eps)
    int idx = (blockIdx.x - 512) * 256 + t;   // 4096 = b*512+oc
    int b = idx >> 9, oc = idx & 511;
    const float4* wq = (const float4*)(wsq + oc * 512);
    const float4* sp = (const float4*)(s + b * 512);
    float acc = 0.f;
    #pragma unroll 4
    for (int k = 0; k < 128; ++k) {
      float4 a = wq[k], c = sp[k];
      acc += a.x * c.x * c.x + a.y * c.y * c.y + a.z * c.z * c.z + a.w * c.w * c.w;
    }
    dscale[idx] = CONV_SCALE * rsqrtf(CONV_SCALE * CONV_SCALE * acc + 1e-8f);
  }
}

// ---- k_conv: implicit-GEMM conv, mfma_f32_32x32x16_bf16 (exact R7 structure).
// Block 64oc x 8rows x 64px, 4 waves; wave = 4rows x 32px x 64oc, acc[4][2] f32x16.
// BK=16, A+B LDS double-buffered; STAGE(t+1) before COMPUTE(t); 1 barrier/step.
// NEW (single change): half-period s_sleep stagger for the second co-resident
// block (pairs are (i, i+256) => parity bit = blockIdx.z & 4) to de-phase-lock
// the two blocks' LDS-burst / MFMA-burst cycles so the pipes overlap.
#define ABYTES 18432
#define BUFB   39552
#define SMEMSZ (2 * BUFB + 256)
__global__ __launch_bounds__(256, 2) void k_conv(
    const ushort* __restrict__ wb, const ushort* __restrict__ xsb,
    const float* __restrict__ dscale, const float* __restrict__ zerobuf,
    float* __restrict__ out) {
  const int yb = blockIdx.x, ocb = blockIdx.y, b = blockIdx.z;
  const int t = threadIdx.x;
  const int wv = t >> 6, l = t & 63;
  const int lc = l & 31, lh = l >> 5;
  const int wvr = wv >> 1, wvp = wv & 1;
  const int y0 = yb * 8, oc0 = ocb * 64;

  extern __shared__ char smem[];
  float* dss = (float*)(smem + 2 * BUFB);
  if (t < 64) dss[t] = dscale[b * 512 + oc0 + t];

  f32x16 acc[4][2];
  #pragma unroll
  for (int rr = 0; rr < 4; ++rr)
    #pragma unroll
    for (int ocf = 0; ocf < 2; ++ocf)
      #pragma unroll
      for (int k = 0; k < 16; ++k)
        acc[rr][ocf][k] = 0.f;

  // A staging: 1152 chunks (4 full iters + t<128)
  const char* asrc[5];
  #pragma unroll
  for (int i = 0; i < 5; ++i) {
    int cid = i * 256 + t;
    int tap = cid >> 7, cc = cid & 127;
    int oc_l = cc >> 1, h = cc & 1;
    asrc[i] = (const char*)wb + (size_t)tap * 524288 + (size_t)(oc0 + oc_l) * 32 + h * 16;
  }
  // B staging: 1320 chunks = 10 rows x 132 (cols 0,1,130,131 = zero border)
  const char* bsrc[6];
  int bstride[6];
  #pragma unroll
  for (int i = 0; i < 6; ++i) {
    int cid = i * 256 + t;
    int r = cid / 132, rem = cid - r * 132;
    int yy = y0 - 1 + r;
    bool interior = (rem >= 2) && (rem < 130) && ((unsigned)yy < 64u);
    bsrc[i] = interior
        ? (const char*)xsb + (size_t)(b * 64 + yy) * 65536 + (rem - 2) * 16
        : (const char*)zerobuf;
    bstride[i] = interior ? 2048 : 0;
  }

  const int apo = (lc * 2 + lh) * 16;
  const int bco = (wvp * 32 + lc) * 32 + lh * 16;

  auto STAGE = [&](int bo, int icb) {
    char* Ab = smem + bo;
    char* Bb = Ab + ABYTES;
    const int aoff = icb * 16384;
    #pragma unroll
    for (int i = 0; i < 4; ++i)
      gload_lds16(asrc[i] + aoff, Ab + i * 4096 + wv * 1024);
    if (t < 128)
      gload_lds16(asrc[4] + aoff, Ab + 16384 + wv * 1024);
    #pragma unroll
    for (int i = 0; i < 5; ++i)
      gload_lds16(bsrc[i] + icb * bstride[i], Bb + i * 4096 + wv * 1024);
    if (t < 40)
      gload_lds16(bsrc[5] + icb * bstride[5], Bb + 20480);
  };

  auto COMPUTE = [&](int bo) {
    const char* Ab = smem + bo;
    const char* Bb = smem + bo + ABYTES;
    #pragma unroll
    for (int dx = 0; dx < 3; ++dx) {
      bf16x8 bfr[6];
      #pragma unroll
      for (int j = 0; j < 6; ++j)
        bfr[j] = *(const bf16x8*)(Bb + (wvr * 4 + j) * 2112 + dx * 32 + bco);
      bf16x8 af[3][2];
      #pragma unroll
      for (int dy = 0; dy < 3; ++dy)
        #pragma unroll
        for (int ocf = 0; ocf < 2; ++ocf)
          af[dy][ocf] = *(const bf16x8*)(Ab + (dy * 3 + dx) * 2048 + ocf * 1024 + apo);
      #pragma unroll
      for (int dy = 0; dy < 3; ++dy)
        #pragma unroll
        for (int rr = 0; rr < 4; ++rr)
          #pragma unroll
          for (int ocf = 0; ocf < 2; ++ocf)
            acc[rr][ocf] = __builtin_amdgcn_mfma_f32_32x32x16_bf16(
                af[dy][ocf], bfr[rr + dy], acc[rr][ocf], 0, 0, 0);
    }
  };

  STAGE(0, 0);
  __syncthreads();
  // de-phase-lock: second co-resident block sleeps ~half a K-step period once.
  if (b & 4) __builtin_amdgcn_s_sleep(73);   // 73*64 ~ 4672 cyc

  #pragma unroll 1
  for (int it = 0; it < 32; it += 2) {
    STAGE(BUFB, it + 1);
    COMPUTE(0);
    __syncthreads();
    if (it < 30) STAGE(0, it + 2);
    COMPUTE(BUFB);
    __syncthreads();
  }

  // ---- epilogue: 32x32 D layout [m74/m101]: col(px)=lane&31, row(oc)=(reg&3)+8*(reg>>2)+4*(lane>>5)
  #pragma unroll
  for (int rr = 0; rr < 4; ++rr) {
    const int y_row = y0 + wvr * 4 + rr;
    #pragma unroll
    for (int ocf = 0; ocf < 2; ++ocf) {
      #pragma unroll
      for (int reg = 0; reg < 16; ++reg) {
        int oc_l = ocf * 32 + (reg & 3) + 8 * (reg >> 2) + 4 * lh;
        out[(size_t)(b * 512 + oc0 + oc_l) * 4096 + y_row * 64 + wvp * 32 + lc]
            = acc[rr][ocf][reg] * dss[oc_l];
      }
    }
  }
}

extern "C" void kernel_launch(void* const* d_in, const int* in_sizes, int n_in,
                              void* d_out, int out_size, void* d_ws, size_t ws_size,
                              hipStream_t stream) {
  const float* x     = (const float*)d_in[0];  // [8,512,64,64]
  const float* style = (const float*)d_in[1];  // [8,512]
  const float* mw    = (const float*)d_in[2];  // [512,512]
  const float* mb    = (const float*)d_in[3];  // [512]
  const float* wsrc  = (const float*)d_in[4];  // [1,512,512,3,3]
  float* out = (float*)d_out;

  char* ws = (char*)d_ws;
  float*  zerobuf = (float*)(ws + 0);          //    64 B
  float*  s       = (float*)(ws + 256);        //  16 KB
  float*  dscale  = (float*)(ws + 16640);      //  16 KB
  float*  wsq     = (float*)(ws + 33024);      //   1 MB
  ushort* wb      = (ushort*)(ws + 1081600);   // 4.5 MB  [9][32][512][16] bf16
  ushort* xsb     = (ushort*)(ws + 5800192);   //  32 MB  [8][64][32][64][16] bf16

  hipFuncSetAttribute(reinterpret_cast<const void*>(k_conv),
                      hipFuncAttributeMaxDynamicSharedMemorySize, SMEMSZ);

  k_prep<<<dim3(1040), dim3(256), 0, stream>>>(wsrc, wb, wsq, zerobuf, style, mw, mb, s);
  k_pre2<<<dim3(528), dim3(256), 0, stream>>>(x, s, xsb, wsq, dscale);
  k_conv<<<dim3(8, 8, 8), dim3(256), SMEMSZ, stream>>>(wb, xsb, dscale, zerobuf, out);
}